// Round 9
// baseline (154.307 us; speedup 1.0000x reference)
//
#include <hip/hip_runtime.h>
#include <hip/hip_fp16.h>

#define TPB 256
#define NEG_SLOPE 0.2f
#define B1 256          // blocks for hist/place passes
#define DPB 512         // dsts per bucket
#define MAXNB 128       // max buckets

// ---------- helpers ----------
__device__ __forceinline__ int getIdx(const void* p, int is32, long long i) {
  return is32 ? ((const int*)p)[i] : (int)((const long long*)p)[i];
}

// unpack 8 fp16 (loaded as float4) to 8 fp32
__device__ __forceinline__ void unpack8(const float4& r, float* f) {
  const __half2* hp = (const __half2*)&r;
#pragma unroll
  for (int i = 0; i < 4; ++i) {
    float2 t = __half22float2(hp[i]);
    f[2 * i] = t.x;
    f[2 * i + 1] = t.y;
  }
}

// ---------- CSR stage 1: per-block bucket histograms (inline dtype sniff) ----------
__global__ __launch_bounds__(TPB) void k_histA(
    const void* __restrict__ ei, int E, int Etot,
    int* __restrict__ histA, int NB, int CH) {
  __shared__ int lh[MAXNB];
  __shared__ int sflag;
  int b = blockIdx.x, tid = threadIdx.x;
  for (int i = tid; i < NB; i += TPB) lh[i] = 0;
  if (tid < 64) {  // wave 0: sniff int32 vs int64 storage (ids < 2^31)
    const unsigned long long* p = (const unsigned long long*)ei;
    unsigned long long m = __ballot(tid < E && p[tid] > 0xFFFFFFFFULL);
    if (tid == 0) sflag = (m != 0ULL) ? 1 : 0;
  }
  __syncthreads();
  int f = sflag;
  int beg = b * CH, end = min(beg + CH, Etot);
  for (int e = beg + tid; e < end; e += TPB) {
    int d = (e < E) ? getIdx(ei, f, (long long)E + e) : e - E;
    atomicAdd(&lh[d / DPB], 1);
  }
  __syncthreads();
  for (int i = tid; i < NB; i += TPB) histA[b * NB + i] = lh[i];  // [block][bucket]
}

// ---------- CSR stage 2: prefix bases (single block) ----------
__global__ __launch_bounds__(TPB) void k_scanA(
    const int* __restrict__ histA, int* __restrict__ blockBase,
    int* __restrict__ bucketBase, int NB) {
  __shared__ int sh[TPB];
  int t = threadIdx.x;
  int tot = 0;
  if (t < NB) {
    int run = 0;
    for (int b = 0; b < B1; ++b) {           // coalesced: histA[b*NB + t]
      int v = histA[b * NB + t];
      blockBase[b * NB + t] = run;           // intra-bucket prefix over blocks
      run += v;
    }
    tot = run;
  }
  sh[t] = tot;
  __syncthreads();
  for (int off = 1; off < TPB; off <<= 1) {
    int v = (t >= off) ? sh[t - off] : 0;
    __syncthreads();
    sh[t] += v;
    __syncthreads();
  }
  if (t < NB) bucketBase[t] = sh[t] - tot;   // exclusive
  if (t == TPB - 1) bucketBase[NB] = sh[TPB - 1];  // == Etot
}

// ---------- CSR stage 3: place (src,dst) int2 pairs grouped by bucket ----------
__global__ __launch_bounds__(TPB) void k_placeB(
    const void* __restrict__ ei, int E, int Etot,
    const int* __restrict__ blockBase, const int* __restrict__ bucketBase,
    int2* __restrict__ pairs, int NB, int CH) {
  __shared__ int cur[MAXNB];
  __shared__ int sflag;
  int b = blockIdx.x, tid = threadIdx.x;
  for (int i = tid; i < NB; i += TPB) cur[i] = blockBase[b * NB + i] + bucketBase[i];
  if (tid < 64) {
    const unsigned long long* p = (const unsigned long long*)ei;
    unsigned long long m = __ballot(tid < E && p[tid] > 0xFFFFFFFFULL);
    if (tid == 0) sflag = (m != 0ULL) ? 1 : 0;
  }
  __syncthreads();
  int f = sflag;
  int beg = b * CH, end = min(beg + CH, Etot);
  for (int e = beg + tid; e < end; e += TPB) {
    int s, d;
    if (e < E) {
      s = getIdx(ei, f, e);
      d = getIdx(ei, f, (long long)E + e);
    } else {
      s = d = e - E;
    }
    int pos = atomicAdd(&cur[d / DPB], 1);
    pairs[pos] = make_int2(s, d);
  }
}

// ---------- CSR stage 4: per-bucket hist+scan -> rowptr, then place csr_src ----------
__global__ __launch_bounds__(DPB) void k_bucket(
    const int2* __restrict__ pairs, const int* __restrict__ bucketBase,
    int* __restrict__ rowptr, int* __restrict__ csr_src, int N, int Etot) {
  __shared__ int cnt[DPB];
  __shared__ int sc[DPB];
  int g = blockIdx.x, tid = threadIdx.x;
  int base = g * DPB;
  int nd = N - base; if (nd > DPB) nd = DPB;
  cnt[tid] = 0;
  __syncthreads();
  int beg = bucketBase[g], end = bucketBase[g + 1];
  for (int j = beg + tid; j < end; j += DPB)
    atomicAdd(&cnt[pairs[j].y & (DPB - 1)], 1);
  __syncthreads();
  sc[tid] = cnt[tid];
  __syncthreads();
  for (int off = 1; off < DPB; off <<= 1) {
    int v = (tid >= off) ? sc[tid - off] : 0;
    __syncthreads();
    sc[tid] += v;
    __syncthreads();
  }
  int excl = beg + sc[tid] - cnt[tid];
  if (tid < nd) rowptr[base + tid] = excl;
  if (g == 0 && tid == 0) rowptr[N] = Etot;
  __syncthreads();
  cnt[tid] = excl;  // becomes cursor
  __syncthreads();
  for (int j = beg + tid; j < end; j += DPB) {
    int2 p = pairs[j];
    int pos = atomicAdd(&cnt[p.y & (DPB - 1)], 1);
    csr_src[pos] = p.x;
  }
}

// ---------- layer 1: h1 = x @ W1 (fp16 out), fused alpha dots ----------
__global__ __launch_bounds__(TPB) void k_gemm1(
    const float* __restrict__ x, const float* __restrict__ W1,
    const float* __restrict__ aS, const float* __restrict__ aD,
    __half* __restrict__ h1, float* __restrict__ asrc, float* __restrict__ adst, int N) {
  __shared__ float Wl[64 * 64];
  __shared__ float xr[4][64];
  int t = threadIdx.x;
  for (int i = t; i < 64 * 64; i += TPB) Wl[i] = W1[i];
  int w = t >> 6, lane = t & 63;
  int node = blockIdx.x * 4 + w;
  if (node < N) xr[w][lane] = x[(size_t)node * 64 + lane];
  __syncthreads();
  if (node >= N) return;
  float acc = 0.f;
#pragma unroll
  for (int k = 0; k < 64; ++k) acc = fmaf(xr[w][k], Wl[k * 64 + lane], acc);
  h1[(size_t)node * 64 + lane] = __float2half(acc);
  float vs = acc * aS[lane];
  float vd = acc * aD[lane];
#pragma unroll
  for (int m = 16; m >= 1; m >>= 1) {
    vs += __shfl_xor(vs, m, 64);
    vd += __shfl_xor(vd, m, 64);
  }
  if ((lane & 31) == 0) {
    asrc[node * 2 + (lane >> 5)] = vs;
    adst[node * 2 + (lane >> 5)] = vd;
  }
}

// ---------- fused layer-1 gather + layer-2 linear, two-phase via LDS staging ----------
// Phase 1: lane i handles edge beg+i -> id/alpha loads all issue in parallel;
//          (sid, w0, w1) staged in wave-private LDS (proven same-wave handoff).
// Phase 2: 8-lane groups gather h1 rows; s,w read from LDS (no global latency).
__global__ __launch_bounds__(TPB) void k_gather1f(
    const int* __restrict__ rowptr, const int* __restrict__ csr_src,
    const float* __restrict__ as1, const float* __restrict__ ad1,
    const __half* __restrict__ h1, const float* __restrict__ b1,
    const float* __restrict__ W2, const float* __restrict__ aS2,
    const float* __restrict__ aD2,
    __half* __restrict__ h2, float* __restrict__ as2, float* __restrict__ ad2, int N) {
  __shared__ float W2s[64 * 32];
  __shared__ float aS2s[32], aD2s[32];
  __shared__ float rowBuf[4][64];
  __shared__ int   sSid[4][64];
  __shared__ float sW0[4][64], sW1[4][64];
  int t = threadIdx.x;
  for (int i = t; i < 64 * 32; i += TPB) W2s[i] = W2[i];
  if (t < 32) { aS2s[t] = aS2[t]; aD2s[t] = aD2[t]; }
  __syncthreads();

  int w = t >> 6, lane = t & 63;
  int node = blockIdx.x * 4 + w;
  if (node >= N) return;

  int g8 = lane >> 3, l8 = lane & 7;   // 8 groups of 8 lanes; l8 owns feats [l8*8,l8*8+8)
  float2 adv = *(const float2*)(ad1 + (size_t)node * 2);
  int beg = rowptr[node], end = rowptr[node + 1];
  float a[8] = {0.f, 0.f, 0.f, 0.f, 0.f, 0.f, 0.f, 0.f};
  float d0L = 0.f, d1L = 0.f;
  for (int chunk = beg; chunk < end; chunk += 64) {
    int m = end - chunk; if (m > 64) m = 64;
    if (lane < m) {                      // phase 1: up to 64 edges in parallel
      int sid = csr_src[chunk + lane];
      float2 av = *(const float2*)(as1 + (size_t)sid * 2);
      float v0 = av.x + adv.x, v1 = av.y + adv.y;
      v0 = v0 > 0.f ? v0 : NEG_SLOPE * v0;
      v1 = v1 > 0.f ? v1 : NEG_SLOPE * v1;
      float w0 = __expf(v0), w1 = __expf(v1);
      d0L += w0; d1L += w1;
      sSid[w][lane] = sid;
      sW0[w][lane] = w0;
      sW1[w][lane] = w1;
    }
    // same-wave LDS write->read handoff (lockstep, in-order LDS pipe)
    for (int j = g8; j < m; j += 8) {    // phase 2: only global op is h1 gather
      int s = sSid[w][j];
      float wgt = (l8 < 4) ? sW0[w][j] : sW1[w][j];  // head = l8>>2
      float4 r = *(const float4*)(h1 + (size_t)s * 64 + l8 * 8);
      float f[8];
      unpack8(r, f);
#pragma unroll
      for (int i = 0; i < 8; ++i) a[i] = fmaf(wgt, f[i], a[i]);
    }
  }
#pragma unroll
  for (int m2 = 1; m2 <= 32; m2 <<= 1) {  // full-wave denominator reduce
    d0L += __shfl_xor(d0L, m2, 64);
    d1L += __shfl_xor(d1L, m2, 64);
  }
#pragma unroll
  for (int m2 = 8; m2 <= 32; m2 <<= 1) {  // sum the 8 edge-groups
#pragma unroll
    for (int i = 0; i < 8; ++i) a[i] += __shfl_xor(a[i], m2, 64);
  }
  if (g8 == 0) {  // lanes 0..7 own features [l8*8, l8*8+8)
    float inv = 1.f / (((l8 < 4) ? d0L : d1L) + 1e-16f);
#pragma unroll
    for (int i = 0; i < 8; ++i) {
      float o = fmaf(a[i], inv, b1[l8 * 8 + i]);
      rowBuf[w][l8 * 8 + i] = o > 0.f ? o : 0.f;
    }
  }
  // wave-internal LDS handoff: same wave, in-order LDS pipe -> visible
  int c = lane & 31, half = lane >> 5;
  float acc2 = 0.f;
#pragma unroll
  for (int k = 0; k < 32; ++k)
    acc2 = fmaf(rowBuf[w][half * 32 + k], W2s[(half * 32 + k) * 32 + c], acc2);
  acc2 += __shfl_xor(acc2, 32, 64);  // full dot in all lanes
  if (half == 0) h2[(size_t)node * 32 + c] = __float2half(acc2);
  float vs = acc2 * aS2s[c];
  float vd = acc2 * aD2s[c];
#pragma unroll
  for (int m = 16; m >= 1; m >>= 1) {
    vs += __shfl_xor(vs, m, 64);
    vd += __shfl_xor(vd, m, 64);
  }
  if (lane == 0) {
    as2[node] = vs;
    ad2[node] = vd;
  }
}

// ---------- layer 2 gather: two-phase via LDS staging, 4-lane group per edge ----------
__global__ __launch_bounds__(TPB) void k_gather2(
    const int* __restrict__ rowptr, const int* __restrict__ csr_src,
    const float* __restrict__ as2, const float* __restrict__ ad2,
    const __half* __restrict__ h2, const float* __restrict__ b,
    float* __restrict__ out, int N) {
  __shared__ int   sS[4][64];
  __shared__ float sWv[4][64];
  int w = threadIdx.x >> 6;
  int wid = (int)((blockIdx.x * (unsigned)TPB + threadIdx.x) >> 6);
  int lane = threadIdx.x & 63;
  if (wid >= N) return;
  int g4 = lane >> 2, l4 = lane & 3;   // 16 groups of 4 lanes; l4 owns feats [l4*8,l4*8+8)
  float ad = ad2[wid];
  int beg = rowptr[wid], end = rowptr[wid + 1];
  float a[8] = {0.f, 0.f, 0.f, 0.f, 0.f, 0.f, 0.f, 0.f};
  float dL = 0.f;
  for (int chunk = beg; chunk < end; chunk += 64) {
    int m = end - chunk; if (m > 64) m = 64;
    if (lane < m) {                      // phase 1
      int sid = csr_src[chunk + lane];
      float v = as2[sid] + ad;
      v = v > 0.f ? v : NEG_SLOPE * v;
      float wv = __expf(v);
      dL += wv;
      sS[w][lane] = sid;
      sWv[w][lane] = wv;
    }
    for (int j = g4; j < m; j += 16) {   // phase 2
      int s = sS[w][j];
      float wgt = sWv[w][j];
      float4 r = *(const float4*)(h2 + (size_t)s * 32 + l4 * 8);
      float f[8];
      unpack8(r, f);
#pragma unroll
      for (int i = 0; i < 8; ++i) a[i] = fmaf(wgt, f[i], a[i]);
    }
  }
#pragma unroll
  for (int m2 = 1; m2 <= 32; m2 <<= 1) dL += __shfl_xor(dL, m2, 64);
#pragma unroll
  for (int m2 = 4; m2 <= 32; m2 <<= 1) {
#pragma unroll
    for (int i = 0; i < 8; ++i) a[i] += __shfl_xor(a[i], m2, 64);
  }
  if (g4 == 0) {  // lanes 0..3 own features [l4*8, l4*8+8)
    float inv = 1.f / (dL + 1e-16f);
    float o[8];
#pragma unroll
    for (int i = 0; i < 8; ++i) o[i] = fmaf(a[i], inv, b[l4 * 8 + i]);
    float4* dst = (float4*)(out + (size_t)wid * 32 + l4 * 8);
    dst[0] = make_float4(o[0], o[1], o[2], o[3]);
    dst[1] = make_float4(o[4], o[5], o[6], o[7]);
  }
}

extern "C" void kernel_launch(void* const* d_in, const int* in_sizes, int n_in,
                              void* d_out, int out_size, void* d_ws, size_t ws_size,
                              hipStream_t stream) {
  const float* x   = (const float*)d_in[0];
  const void*  ei  = d_in[1];
  const float* W1  = (const float*)d_in[2];
  const float* aS1 = (const float*)d_in[3];
  const float* aD1 = (const float*)d_in[4];
  const float* b1  = (const float*)d_in[5];
  const float* W2  = (const float*)d_in[6];
  const float* aS2 = (const float*)d_in[7];
  const float* aD2 = (const float*)d_in[8];
  const float* b2  = (const float*)d_in[9];
  float* out = (float*)d_out;

  int N = in_sizes[0] / 64;
  int E = in_sizes[1] / 2;
  int Etot = E + N;
  int NB = (N + DPB - 1) / DPB;         // dst buckets
  int CH = (Etot + B1 - 1) / B1;        // edges per hist/place block

  float* W = (float*)d_ws;
  size_t o = 0;
  __half* h1 = (__half*)(W + o); o += (size_t)N * 32;   // N*64 halfs
  // pairs (int2, Etot) shares storage with h2 (N*32 halfs): disjoint lifetimes
  size_t regB = (size_t)(2 * (size_t)Etot > (size_t)N * 16 ? 2 * (size_t)Etot : (size_t)N * 16);
  int2* pairs = (int2*)(W + o);
  __half* h2  = (__half*)(W + o);
  o += regB;
  float* as1  = W + o; o += (size_t)N * 2;
  float* ad1  = W + o; o += (size_t)N * 2;
  float* as2  = W + o; o += (size_t)N;
  float* ad2  = W + o; o += (size_t)N;
  int* ip = (int*)(W + o);
  size_t io = 0;
  int* histA      = ip + io; io += (size_t)NB * B1;
  int* blockBase  = ip + io; io += (size_t)NB * B1;
  int* bucketBase = ip + io; io += NB + 1;
  int* rowptr     = ip + io; io += N + 1;
  int* csr_src    = ip + io; io += Etot;

  // CSR build: LDS-binned counting sort, no global return-atomics
  k_histA<<<B1, TPB, 0, stream>>>(ei, E, Etot, histA, NB, CH);
  k_scanA<<<1, TPB, 0, stream>>>(histA, blockBase, bucketBase, NB);
  k_placeB<<<B1, TPB, 0, stream>>>(ei, E, Etot, blockBase, bucketBase, pairs, NB, CH);
  k_bucket<<<NB, DPB, 0, stream>>>(pairs, bucketBase, rowptr, csr_src, N, Etot);

  // layer 1 + fused layer-2 linear
  k_gemm1<<<(N + 3) / 4, TPB, 0, stream>>>(x, W1, aS1, aD1, h1, as1, ad1, N);
  k_gather1f<<<(N + 3) / 4, TPB, 0, stream>>>(rowptr, csr_src, as1, ad1, h1, b1,
                                              W2, aS2, aD2, h2, as2, ad2, N);

  // layer 2 gather -> output
  k_gather2<<<(N * 64 + TPB - 1) / TPB, TPB, 0, stream>>>(rowptr, csr_src, as2, ad2, h2, b2, out, N);
}